// Round 6
// baseline (387.639 us; speedup 1.0000x reference)
//
#include <hip/hip_runtime.h>
#include <stdint.h>

// ---------------------------------------------------------------------------
// PDG2Seq_GCN: B=16, N=1024, C=O=64, D=10, CHEB_K=2 (K=5 stacked terms)
// Round 12 (= R11 + streamed A-load): R11's counters showed mega at 212 us,
// 2.8% MFMA/VALU, 645 GB/s — traffic at the floor but DRAM-inefficient:
// the A-load gathered 64B chunks at 4KB stride (≈32K concurrent streams
// chip-wide -> row-buffer thrash, ~1 TB/s). Fix: A-load v2 streams each
// wave's 16 CONTIGUOUS adj rows in 1KB contiguous bursts via global_load_lds
// into a wave-private LDS slab ([16][256] fp32, 4 slabs), then extracts MFMA
// fragments wave-locally (ds_read_b128 + in-reg RNE). Rule learned
// (R6 vs R7 vs R11): adj must be read in large contiguous bursts.
// Everything else identical to R11 (passed, absmax 1024).
// ---------------------------------------------------------------------------

typedef __attribute__((ext_vector_type(4))) float f32x4;
typedef __attribute__((ext_vector_type(8))) short s16x8;
typedef __attribute__((ext_vector_type(8))) __bf16 bf16x8;

__device__ __forceinline__ unsigned short f2bf(float f) {
  union { float f; uint32_t u; } v; v.f = f;
  uint32_t r = v.u + 0x7FFFu + ((v.u >> 16) & 1u);   // RNE
  return (unsigned short)(r >> 16);
}
__device__ __forceinline__ uint32_t pack2(float a, float b) {
  return (uint32_t)f2bf(a) | ((uint32_t)f2bf(b) << 16);
}

union FragU { s16x8 s; bf16x8 b; uint32_t u[4]; };

__device__ __forceinline__ void async_cp16(const void* g, void* l) {
  __builtin_amdgcn_global_load_lds(
      (const __attribute__((address_space(1))) void*)g,
      (__attribute__((address_space(3))) void*)l, 16, 0, 0);
}

// ---------------------------------------------------------------------------
__global__ __launch_bounds__(64) void init_bar(unsigned* bar) {
  if (threadIdx.x < 2) bar[threadIdx.x] = 0u;
}

// Sense-reversal grid barrier for exactly 256 blocks. bar[0]=cnt, bar[1]=gen.
__device__ __forceinline__ void gbar(unsigned* bar) {
  __syncthreads();
  if (threadIdx.x == 0) {
    __threadfence();   // publish this block's stores
    unsigned g = __hip_atomic_load(bar + 1, __ATOMIC_RELAXED,
                                   __HIP_MEMORY_SCOPE_AGENT);
    unsigned a = __hip_atomic_fetch_add(bar, 1u, __ATOMIC_ACQ_REL,
                                        __HIP_MEMORY_SCOPE_AGENT);
    if (a == 255u) {
      __hip_atomic_store(bar, 0u, __ATOMIC_RELAXED, __HIP_MEMORY_SCOPE_AGENT);
      __hip_atomic_store(bar + 1, g + 1u, __ATOMIC_RELEASE,
                         __HIP_MEMORY_SCOPE_AGENT);
    } else {
      while (__hip_atomic_load(bar + 1, __ATOMIC_RELAXED,
                               __HIP_MEMORY_SCOPE_AGENT) == g)
        __builtin_amdgcn_s_sleep(2);
    }
    __threadfence();   // acquire: invalidate stale caches before reads
  }
  __syncthreads();
}

// ---------------------------------------------------------------------------
// hop: out[128 rows][64] = A(regs) @ X[1024x64], B staged 8KB/stage from
// XT [c][n] layout, 3-deep buffers, counted vmcnt(1), XOR chunk swizzle
// (pre-swizzled global source, linear LDS dest, swizzled ds_read).
// ---------------------------------------------------------------------------
__device__ __forceinline__ void hop128(char* smem, const FragU (&af)[32],
                                       const unsigned short* __restrict__ XT,
                                       unsigned short* __restrict__ Xoutb,
                                       unsigned short* __restrict__ XTout,
                                       const int write_xt) {
  const int tid = threadIdx.x;
  const int wave = tid >> 6, lane = tid & 63;
  const int l15 = lane & 15, q = lane >> 4, sw = l15 & 7;

  unsigned short* const Bst = (unsigned short*)smem;   // [3][64 c][64 m]
  const int c = wave * 8 + (lane >> 3);
  const unsigned short* bsrc =
      XT + (size_t)c * 1024 + ((lane & 7) ^ (c & 7)) * 8;
  unsigned short* const bdst = Bst + wave * 512;       // HW adds lane*16B

  f32x4 acc[4];
#pragma unroll
  for (int t = 0; t < 4; ++t) acc[t] = (f32x4){0.f, 0.f, 0.f, 0.f};

  asm volatile("s_waitcnt vmcnt(0)" ::: "memory");     // clean vm counter
  async_cp16(bsrc, bdst);
  async_cp16(bsrc + 64, bdst + 4096);
#pragma unroll
  for (int kt = 0; kt < 16; ++kt) {
    if (kt == 15) asm volatile("s_waitcnt vmcnt(0)" ::: "memory");
    else          asm volatile("s_waitcnt vmcnt(1)" ::: "memory");
    __builtin_amdgcn_sched_barrier(0);
    __builtin_amdgcn_s_barrier();                      // all waves: kt landed
    __builtin_amdgcn_sched_barrier(0);
    if (kt + 2 < 16)
      async_cp16(bsrc + (kt + 2) * 64, bdst + ((kt + 2) % 3) * 4096);
    const unsigned short* Bb = Bst + (kt % 3) * 4096 + l15 * 64;
#pragma unroll
    for (int kk = 0; kk < 2; ++kk) {
      const int p = ((kk * 4 + q) ^ sw) * 8;
#pragma unroll
      for (int t = 0; t < 4; ++t) {
        FragU bf;
        bf.s = *(const s16x8*)(Bb + t * 1024 + p);
        acc[t] = __builtin_amdgcn_mfma_f32_16x16x32_bf16(
            af[kt * 2 + kk].b, bf.b, acc[t], 0, 0, 0);
      }
    }
  }

  // Epilogue: 128x64 tile transpose via LDS (reuse stage memory)
  __syncthreads();
  float (*tile)[65] = (float(*)[65])smem;              // 33.3 KB
#pragma unroll
  for (int t = 0; t < 4; ++t)
#pragma unroll
    for (int rr = 0; rr < 4; ++rr)
      tile[wave * 16 + q * 4 + rr][t * 16 + l15] = acc[t][rr];
  __syncthreads();
  {
    const int row = tid >> 2, cb = (tid & 3) * 16;
    s16x8 s0, s1;
#pragma unroll
    for (int j = 0; j < 8; ++j) {
      s0[j] = (short)f2bf(tile[row][cb + j]);
      s1[j] = (short)f2bf(tile[row][cb + 8 + j]);
    }
    unsigned short* outp = Xoutb + (size_t)row * 64 + cb;
    *(s16x8*)outp = s0;
    *(s16x8*)(outp + 8) = s1;
  }
  if (write_xt) {
    const int c2 = tid >> 3, nch = (tid & 7) * 16;
    s16x8 s0, s1;
#pragma unroll
    for (int j = 0; j < 8; ++j) {
      s0[j] = (short)f2bf(tile[nch + j][c2]);
      s1[j] = (short)f2bf(tile[nch + 8 + j][c2]);
    }
    unsigned short* xtp = XTout + (size_t)c2 * 1024 + nch;
    *(s16x8*)xtp = s0;
    *(s16x8*)(xtp + 8) = s1;
  }
}

// ---------------------------------------------------------------------------
__global__ __launch_bounds__(512, 2) void mega(
    const float* __restrict__ adj, const float* __restrict__ x,
    const float* __restrict__ emb, const float* __restrict__ wp,
    const float* __restrict__ bp, float* __restrict__ out,
    unsigned short* __restrict__ XT0, unsigned short* __restrict__ X0b,
    unsigned short* __restrict__ XT1, unsigned short* __restrict__ X1b,
    unsigned short* __restrict__ X2b, unsigned short* __restrict__ wpTb,
    unsigned* bar) {
  __shared__ __align__(16) char smem[131072];
  const int tid = threadIdx.x, bid = blockIdx.x;
  const int wave = tid >> 6, lane = tid & 63;
  const int l15 = lane & 15, q = lane >> 4;

  // ---------------- P0: prep (x -> XT0 + X0b; wp -> swizzled wpTb) --------
  if (tid < 256) {
    unsigned short (*tl)[72] = (unsigned short(*)[72])smem;
    const int b = bid >> 4, n0 = (bid & 15) * 64;
    const int c4 = (tid & 15) * 4;
#pragma unroll
    for (int i = 0; i < 4; ++i) {
      const int row = (tid >> 4) + i * 16;
      f32x4 v = *(const f32x4*)(x + ((size_t)(b * 1024 + n0 + row)) * 64 + c4);
      const uint32_t w0 = pack2(v[0], v[1]);
      const uint32_t w1 = pack2(v[2], v[3]);
      *(uint32_t*)&tl[row][c4] = w0;
      *(uint32_t*)&tl[row][c4 + 2] = w1;
      const uint64_t wq = (uint64_t)w0 | ((uint64_t)w1 << 32);
      *(uint64_t*)(X0b + ((size_t)(b * 1024 + n0 + row)) * 64 + c4) = wq;
    }
  } else if (bid < 50) {
    float (*tlw)[65] = (float(*)[65])(smem + 18432);
    const int t2 = tid - 256;
    const int d = bid / 5, ki0 = (bid % 5) * 64;
    const float* src = wp + (size_t)d * 20480;
    const int o4 = (t2 & 15) * 4;
#pragma unroll
    for (int i = 0; i < 4; ++i) {
      const int row = (t2 >> 4) + i * 16;
      f32x4 v = *(const f32x4*)(src + (size_t)(ki0 + row) * 64 + o4);
      tlw[row][o4] = v[0]; tlw[row][o4 + 1] = v[1];
      tlw[row][o4 + 2] = v[2]; tlw[row][o4 + 3] = v[3];
    }
  }
  __syncthreads();
  if (tid < 256) {
    unsigned short (*tl)[72] = (unsigned short(*)[72])smem;
    const int b = bid >> 4, n0 = (bid & 15) * 64;
    const int cc = tid >> 2, nch = (tid & 3) * 16;
    s16x8 s0, s1;
#pragma unroll
    for (int j = 0; j < 8; ++j) {
      s0[j] = (short)tl[nch + j][cc];
      s1[j] = (short)tl[nch + 8 + j][cc];
    }
    unsigned short* p = XT0 + (size_t)(b * 64 + cc) * 1024 + n0 + nch;
    *(s16x8*)p = s0;
    *(s16x8*)(p + 8) = s1;
  } else if (bid < 50) {
    float (*tlw)[65] = (float(*)[65])(smem + 18432);
    const int t2 = tid - 256;
    const int d = bid / 5, ki0 = (bid % 5) * 64;
    const int o = t2 >> 2, kch = (t2 & 3) * 16;
    s16x8 s0, s1;
#pragma unroll
    for (int j = 0; j < 8; ++j) {
      s0[j] = (short)f2bf(tlw[kch + j][o]);
      s1[j] = (short)f2bf(tlw[kch + 8 + j][o]);
    }
    const int c0 = (ki0 + kch) >> 3;                   // 16B chunk index
    unsigned short* base = wpTb + (size_t)d * 24576 + (size_t)o * 384;
    *(s16x8*)(base + ((c0) ^ (o & 7)) * 8) = s0;
    *(s16x8*)(base + ((c0 + 1) ^ (o & 7)) * 8) = s1;
  }
  __syncthreads();   // P1's slab DMAs overwrite the LDS P0 just read

  // ---------------- P1: A-load v2 — streamed via wave-private LDS slab ----
  // Wave w owns 16 contiguous adj rows. Per slab s (k-range s*256..+256):
  // 16 DMA instrs, each a 1KB CONTIGUOUS row-chunk (lane -> +lane*16B),
  // dest linear [16 rows][64 chunks]; source chunk pre-swizzled lane^(row&7)
  // so extraction ds_reads are bank-spread. Then extract 8 frags/lane
  // (row = l15, 2x ds_read_b128 fp32 + in-reg RNE pack -> bf16 frag).
  const int slice = bid >> 3;                          // 0..31
  const int rowbase = (bid & 7) * 128;
  FragU af[32];
  {
    const int r7 = l15 & 7;
    float* const myslab = (float*)smem + wave * 4096;  // 16KB per wave
    const float* const abase =
        adj + ((size_t)slice * 1024 + rowbase + wave * 16) * 1024;
    const float* const rowp = (const float*)smem + wave * 4096 + l15 * 256;
#pragma unroll
    for (int s = 0; s < 4; ++s) {
      if (s) {  // WAR: previous slab's ds_reads must retire before overwrite
        asm volatile("s_waitcnt lgkmcnt(0)" ::: "memory");
        __builtin_amdgcn_sched_barrier(0);
      }
#pragma unroll
      for (int i = 0; i < 16; ++i)
        async_cp16(abase + (size_t)i * 1024 + s * 256 + (lane ^ (i & 7)) * 4,
                   myslab + i * 256);
      asm volatile("s_waitcnt vmcnt(0)" ::: "memory");
      __builtin_amdgcn_sched_barrier(0);
#pragma unroll
      for (int ksp = 0; ksp < 8; ++ksp) {
        const int ch0 = ksp * 8 + ((q * 2) ^ r7);
        const int ch1 = ksp * 8 + ((q * 2 + 1) ^ r7);
        f32x4 lo = *(const f32x4*)(rowp + ch0 * 4);
        f32x4 hi = *(const f32x4*)(rowp + ch1 * 4);
        af[s * 8 + ksp].u[0] = pack2(lo[0], lo[1]);
        af[s * 8 + ksp].u[1] = pack2(lo[2], lo[3]);
        af[s * 8 + ksp].u[2] = pack2(hi[0], hi[1]);
        af[s * 8 + ksp].u[3] = pack2(hi[2], hi[3]);
      }
    }
  }

  gbar(bar);   // XT0/X0b/wpTb ready (and all slab extractions done)

  // ---------------- P2: hop1 ----------------
  hop128(smem, af, XT0 + (size_t)(slice & 15) * 65536,
         X1b + (size_t)slice * 65536 + (size_t)rowbase * 64,
         XT1 + (size_t)slice * 65536 + rowbase, 1);

  gbar(bar);   // XT1 ready

  // ---------------- P3: hop2 (same A-frags, zero reload) ----------------
  hop128(smem, af, XT1 + (size_t)slice * 65536,
         X2b + (size_t)slice * 65536 + (size_t)rowbase * 64,
         (unsigned short*)0, 0);

  gbar(bar);   // X1b/X2b ready

  // ---------------- P4: final ----------------
  {
    unsigned short (*wd)[384] = (unsigned short(*)[384])smem;   // 48 KB
    const int nd = wave >> 1, oh = wave & 1;
    const int n = bid * 4 + nd;
    const int sw2 = l15 & 7;

    FragU af10[10];
#pragma unroll
    for (int ks = 0; ks < 10; ++ks) {
      const int k = ks >> 1;
      const int cc0 = (ks & 1) * 32 + q * 8;
      const unsigned short* srcp;
      if (k == 0) {
        srcp = X0b + ((size_t)l15 * 1024 + n) * 64 + cc0;
      } else {
        const unsigned short* arr = (k == 1 || k == 3) ? X1b : X2b;
        const int s = (k >= 3) ? 1 : 0;
        srcp = arr + ((size_t)(s * 16 + l15) * 1024 + n) * 64 + cc0;
      }
      af10[ks].s = *(const s16x8*)srcp;
    }

    f32x4 acc0 = {0.f, 0.f, 0.f, 0.f}, acc1 = {0.f, 0.f, 0.f, 0.f};
    // Per-lane global source (global_load_lds gathers per-lane; LDS dest is
    // wave-uniform + lane*16B).
    const unsigned short* wsrc = wpTb + (size_t)wave * 3072 + lane * 8;
    unsigned short* wdst = (unsigned short*)smem + wave * 3072;
#pragma unroll 1
    for (int d = 0; d < 10; ++d) {
      if (d) __syncthreads();                          // WAR vs prev compute
#pragma unroll
      for (int i = 0; i < 6; ++i)
        async_cp16(wsrc + (size_t)d * 24576 + i * 512, wdst + i * 512);
      asm volatile("s_waitcnt vmcnt(0)" ::: "memory");
      __builtin_amdgcn_sched_barrier(0);
      __syncthreads();
      f32x4 t0 = {0.f, 0.f, 0.f, 0.f}, t1 = {0.f, 0.f, 0.f, 0.f};
#pragma unroll
      for (int ks = 0; ks < 10; ++ks) {
        const int p = ((ks * 4 + q) ^ sw2) * 8;
        FragU b0, b1;
        b0.s = *(const s16x8*)&wd[oh * 32 + l15][p];
        b1.s = *(const s16x8*)&wd[oh * 32 + 16 + l15][p];
        t0 = __builtin_amdgcn_mfma_f32_16x16x32_bf16(af10[ks].b, b0.b, t0,
                                                     0, 0, 0);
        t1 = __builtin_amdgcn_mfma_f32_16x16x32_bf16(af10[ks].b, b1.b, t1,
                                                     0, 0, 0);
      }
      const float e = emb[n * 10 + d];
#pragma unroll
      for (int rr = 0; rr < 4; ++rr) {
        acc0[rr] += e * t0[rr];
        acc1[rr] += e * t1[rr];
      }
    }

#pragma unroll
    for (int tt = 0; tt < 2; ++tt) {
      const int o = oh * 32 + tt * 16 + l15;
      float bv = 0.f;
#pragma unroll
      for (int d = 0; d < 10; ++d) bv += emb[n * 10 + d] * bp[d * 64 + o];
#pragma unroll
      for (int rr = 0; rr < 4; ++rr) {
        const int bb = q * 4 + rr;
        const float a = tt ? acc1[rr] : acc0[rr];
        out[((size_t)bb * 1024 + n) * 64 + o] = a + bv;
      }
    }
  }
}

// ---------------------------------------------------------------------------
extern "C" void kernel_launch(void* const* d_in, const int* in_sizes, int n_in,
                              void* d_out, int out_size, void* d_ws,
                              size_t ws_size, hipStream_t stream) {
  const float* x   = (const float*)d_in[0];   // [16,1024,64]
  const float* adj = (const float*)d_in[1];   // [2,16,1024,1024]
  const float* emb = (const float*)d_in[2];   // [1024,10]
  const float* wp  = (const float*)d_in[3];   // [10,5,64,64]
  const float* bp  = (const float*)d_in[4];   // [10,64]
  float* out = (float*)d_out;                 // [16,1024,64]

  char* ws = (char*)d_ws;
  unsigned short* XT0  = (unsigned short*)(ws);                      // 2 MB
  unsigned short* X0b  = (unsigned short*)(ws + ((size_t)2 << 20));  // 2 MB
  unsigned short* XT1  = (unsigned short*)(ws + ((size_t)4 << 20));  // 4 MB
  unsigned short* X1b  = (unsigned short*)(ws + ((size_t)8 << 20));  // 4 MB
  unsigned short* X2b  = (unsigned short*)(ws + ((size_t)12 << 20)); // 4 MB
  unsigned short* wpTb = (unsigned short*)(ws + ((size_t)16 << 20)); // 480 KB
  unsigned* bar        = (unsigned*)(ws + ((size_t)17 << 20));       // 8 B

  init_bar<<<dim3(1), dim3(64), 0, stream>>>(bar);

  void* args[] = {(void*)&adj, (void*)&x,   (void*)&emb, (void*)&wp,
                  (void*)&bp,  (void*)&out, (void*)&XT0, (void*)&X0b,
                  (void*)&XT1, (void*)&X1b, (void*)&X2b, (void*)&wpTb,
                  (void*)&bar};
  hipLaunchCooperativeKernel((void*)mega, dim3(256), dim3(512), args, 0,
                             stream);
}

// Round 7
// 259.685 us; speedup vs baseline: 1.4927x; 1.4927x over previous
//
#include <hip/hip_runtime.h>
#include <stdint.h>

// ---------------------------------------------------------------------------
// PDG2Seq_GCN: B=16, N=1024, C=O=64, D=10, CHEB_K=2 (K=5 stacked terms)
// Round 13: revert to the R6 multi-kernel skeleton (occupancy-friendly,
// proven 117 us of kernel time; mega/persistent design was 2x worse from
// latency serialization at 1 block/CU). Grafted improvements, each proven
// in isolation: (1) WT (40MB write + 40MB read + wgen) dropped — final
// regenerates per-node weights per-d from LDS-staged swizzled wpTb (R12's
// P4, passed); (2) bf16 node-major intermediates X0b/X1b/X2b (R8, passed)
// so final staging is u32 copies. Hops identical to R6 (bf16 adjb via
// global_load_lds, 2-buf, syncthreads drain, XOR swizzle).
// Launches: cvt_adj, prep, hop1, hop2, final (5 kernels).
// ---------------------------------------------------------------------------

typedef __attribute__((ext_vector_type(4))) float f32x4;
typedef __attribute__((ext_vector_type(8))) short s16x8;
typedef __attribute__((ext_vector_type(8))) __bf16 bf16x8;

__device__ __forceinline__ unsigned short f2bf(float f) {
  union { float f; uint32_t u; } v; v.f = f;
  uint32_t r = v.u + 0x7FFFu + ((v.u >> 16) & 1u);   // RNE
  return (unsigned short)(r >> 16);
}
__device__ __forceinline__ uint32_t pack2(float a, float b) {
  return (uint32_t)f2bf(a) | ((uint32_t)f2bf(b) << 16);
}

union FragU { s16x8 s; bf16x8 b; uint32_t u[4]; };

__device__ __forceinline__ void async_cp16(const void* g, void* l) {
  __builtin_amdgcn_global_load_lds(
      (const __attribute__((address_space(1))) void*)g,
      (__attribute__((address_space(3))) void*)l, 16, 0, 0);
}

// ---------------------------------------------------------------------------
// K0 cvt_adj: adj f32 [33554432] -> adjb bf16. Streaming, grid-stride.
// ---------------------------------------------------------------------------
__global__ __launch_bounds__(256) void cvt_adj(const float* __restrict__ adj,
                                               unsigned short* __restrict__ adjb) {
  const size_t stride = (size_t)gridDim.x * 256 * 8;
  for (size_t p = ((size_t)blockIdx.x * 256 + threadIdx.x) * 8;
       p < 33554432u; p += stride) {
    f32x4 a = *(const f32x4*)(adj + p);
    f32x4 b = *(const f32x4*)(adj + p + 4);
    union { s16x8 s; uint32_t u[4]; } o;
    o.u[0] = pack2(a[0], a[1]);
    o.u[1] = pack2(a[2], a[3]);
    o.u[2] = pack2(b[0], b[1]);
    o.u[3] = pack2(b[2], b[3]);
    *(s16x8*)(adjb + p) = o.s;
  }
}

// ---------------------------------------------------------------------------
// K1 prep: blocks 0..255: x -> XT0 bf16 [b][c][n] + X0b bf16 [b][n][c];
//          blocks 256..305: wp -> swizzled bf16 wpTb [d][o][384-chunkspace].
// ---------------------------------------------------------------------------
__global__ __launch_bounds__(256) void prep(const float* __restrict__ x,
                                            const float* __restrict__ wp,
                                            unsigned short* __restrict__ XT0,
                                            unsigned short* __restrict__ X0b,
                                            unsigned short* __restrict__ wpTb) {
  __shared__ __align__(16) char smem[17160];
  const int tid = threadIdx.x;
  const int bid = blockIdx.x;
  if (bid < 256) {
    unsigned short (*tl)[72] = (unsigned short(*)[72])smem;
    const int b = bid >> 4, n0 = (bid & 15) * 64;
    {
      const int c4 = (tid & 15) * 4;
#pragma unroll
      for (int i = 0; i < 4; ++i) {
        const int row = (tid >> 4) + i * 16;
        f32x4 v =
            *(const f32x4*)(x + ((size_t)(b * 1024 + n0 + row)) * 64 + c4);
        const uint32_t w0 = pack2(v[0], v[1]);
        const uint32_t w1 = pack2(v[2], v[3]);
        *(uint32_t*)&tl[row][c4]     = w0;
        *(uint32_t*)&tl[row][c4 + 2] = w1;
        const uint64_t wq = (uint64_t)w0 | ((uint64_t)w1 << 32);
        *(uint64_t*)(X0b + ((size_t)(b * 1024 + n0 + row)) * 64 + c4) = wq;
      }
    }
    __syncthreads();
    {
      const int c = tid >> 2;
      const int nch = (tid & 3) * 16;
      s16x8 s0, s1;
#pragma unroll
      for (int j = 0; j < 8; ++j) {
        s0[j] = (short)tl[nch + j][c];
        s1[j] = (short)tl[nch + 8 + j][c];
      }
      unsigned short* p = XT0 + (size_t)(b * 64 + c) * 1024 + n0 + nch;
      *(s16x8*)p = s0;
      *(s16x8*)(p + 8) = s1;
    }
  } else {
    float (*tl)[65] = (float(*)[65])smem;
    const int jj = bid - 256;
    const int d = jj / 5, ki0 = (jj % 5) * 64;
    const float* src = wp + (size_t)d * 20480;
    {
      const int o4 = (tid & 15) * 4;
#pragma unroll
      for (int i = 0; i < 4; ++i) {
        const int row = (tid >> 4) + i * 16;
        f32x4 v = *(const f32x4*)(src + (size_t)(ki0 + row) * 64 + o4);
        tl[row][o4] = v[0]; tl[row][o4 + 1] = v[1];
        tl[row][o4 + 2] = v[2]; tl[row][o4 + 3] = v[3];
      }
    }
    __syncthreads();
    {
      const int o = tid >> 2;
      const int kch = (tid & 3) * 16;
      s16x8 s0, s1;
#pragma unroll
      for (int j = 0; j < 8; ++j) {
        s0[j] = (short)f2bf(tl[kch + j][o]);
        s1[j] = (short)f2bf(tl[kch + 8 + j][o]);
      }
      const int c0 = (ki0 + kch) >> 3;                 // 16B chunk index
      unsigned short* base = wpTb + (size_t)d * 24576 + (size_t)o * 384;
      *(s16x8*)(base + ((c0) ^ (o & 7)) * 8) = s0;
      *(s16x8*)(base + ((c0 + 1) ^ (o & 7)) * 8) = s1;
    }
  }
}

// ---------------------------------------------------------------------------
// hop body (R6-proven): out[64 rows][64] = A[1024x1024]bf16 @ X[1024x64]bf16.
// A+B staged via global_load_lds (4 DMA/stage/wave), 32 KB double-buffered
// LDS, 1 __syncthreads per stage, XOR chunk swizzle on the global source.
// Epilogue writes node-major bf16 Xoutb (+ optional c-major XTout).
// ---------------------------------------------------------------------------
__device__ __forceinline__ void hop_body(
    char* smem, const unsigned short* __restrict__ A,
    const unsigned short* __restrict__ XT, unsigned short* __restrict__ Xoutb,
    unsigned short* __restrict__ XTout, int write_xt, int rowbase) {
  const int tid = threadIdx.x;
  const int wave = tid >> 6, lane = tid & 63;
  const int l15 = lane & 15, q = lane >> 4;

  unsigned short* const Ast = (unsigned short*)smem;          // [2][64][64]
  unsigned short* const Bst = (unsigned short*)smem + 8192;   // [2][64][64]

  const int sub = lane >> 3;            // row-in-8
  const int ch = lane & 7;              // 8-short chunk
  const unsigned short* asrc[2];
  const unsigned short* bsrc[2];
  int ldso[2];
#pragma unroll
  for (int i = 0; i < 2; ++i) {
    const int r = wave * 16 + i * 8 + sub;
    asrc[i] = A + (size_t)(rowbase + r) * 1024 + (ch ^ (r & 7)) * 8;
    bsrc[i] = XT + (size_t)r * 1024 + (ch ^ (r & 7)) * 8;
    ldso[i] = (wave * 16 + i * 8) * 64;
  }

  f32x4 acc[4];
#pragma unroll
  for (int t = 0; t < 4; ++t) acc[t] = (f32x4){0.f, 0.f, 0.f, 0.f};

  auto issue = [&](int s, int k0) {
#pragma unroll
    for (int i = 0; i < 2; ++i) {
      async_cp16(asrc[i] + k0, Ast + s * 4096 + ldso[i]);
      async_cp16(bsrc[i] + k0, Bst + s * 4096 + ldso[i]);
    }
  };
  const int sw = l15 & 7;
  auto compute = [&](int s) {
    const unsigned short* Ab = Ast + s * 4096 + (wave * 16 + l15) * 64;
    const unsigned short* Bb = Bst + s * 4096 + l15 * 64;
#pragma unroll
    for (int h = 0; h < 2; ++h) {
      const int cko = ((h * 4 + q) ^ sw) * 8;
      FragU af;
      af.s = *(const s16x8*)(Ab + cko);
#pragma unroll
      for (int t = 0; t < 4; ++t) {
        FragU bf;
        bf.s = *(const s16x8*)(Bb + t * 1024 + cko);
        acc[t] = __builtin_amdgcn_mfma_f32_16x16x32_bf16(af.b, bf.b, acc[t],
                                                         0, 0, 0);
      }
    }
  };

  issue(0, 0);
#pragma unroll 1
  for (int kt = 0; kt < 16; ++kt) {
    const int cur = kt & 1;
    __syncthreads();                   // stage kt landed (vmcnt drain)
    if (kt + 1 < 16) issue(cur ^ 1, (kt + 1) * 64);
    compute(cur);
  }

  // Epilogue: transpose via LDS (reuse stage memory), bf16 write-out
  __syncthreads();
  float (*tile)[65] = (float(*)[65])smem;
#pragma unroll
  for (int t = 0; t < 4; ++t)
#pragma unroll
    for (int rr = 0; rr < 4; ++rr)
      tile[wave * 16 + q * 4 + rr][t * 16 + l15] = acc[t][rr];
  __syncthreads();

  {  // node-major bf16 [n][c]
    const int row = tid >> 2;
    const int cb = (tid & 3) * 16;
    unsigned short* __restrict__ outp =
        Xoutb + (size_t)(rowbase + row) * 64 + cb;
    s16x8 s0, s1;
#pragma unroll
    for (int j = 0; j < 8; ++j) {
      s0[j] = (short)f2bf(tile[row][cb + j]);
      s1[j] = (short)f2bf(tile[row][cb + 8 + j]);
    }
    *(s16x8*)outp = s0;
    *(s16x8*)(outp + 8) = s1;
  }
  if (write_xt) {  // c-major bf16 [c][n] for next hop
    const int c = tid >> 2;
    const int nch = (tid & 3) * 16;
    unsigned short* __restrict__ xtp = XTout + (size_t)c * 1024 + rowbase + nch;
    s16x8 s0, s1;
#pragma unroll
    for (int j = 0; j < 8; ++j) {
      s0[j] = (short)f2bf(tile[nch + j][c]);
      s1[j] = (short)f2bf(tile[nch + 8 + j][c]);
    }
    *(s16x8*)xtp = s0;
    *(s16x8*)(xtp + 8) = s1;
  }
}

// ---------------------------------------------------------------------------
// K2 hop1: adjb bf16 (LLC-warm from cvt) -> X1b + XT1.
// ---------------------------------------------------------------------------
__global__ __launch_bounds__(256, 4) void hop1_kernel(
    const unsigned short* __restrict__ adjb,
    const unsigned short* __restrict__ XT0, unsigned short* __restrict__ X1b,
    unsigned short* __restrict__ XT1) {
  __shared__ __align__(16) char smem[32768];
  const int bx = blockIdx.x, slice = blockIdx.y, b = slice & 15;
  hop_body(smem, adjb + (size_t)slice * 1048576, XT0 + (size_t)b * 65536,
           X1b + (size_t)slice * 65536, XT1 + (size_t)slice * 65536, 1,
           bx * 64);
}

// ---------------------------------------------------------------------------
// K3 hop2, reversed block order (LLC-hot adjb tail first).
// ---------------------------------------------------------------------------
__global__ __launch_bounds__(256, 4) void hop2_kernel(
    const unsigned short* __restrict__ adjb,
    const unsigned short* __restrict__ XT1, unsigned short* __restrict__ X2b) {
  __shared__ __align__(16) char smem[32768];
  const int bx = 15 - (int)blockIdx.x;
  const int slice = 31 - (int)blockIdx.y;
  hop_body(smem, adjb + (size_t)slice * 1048576, XT1 + (size_t)slice * 65536,
           X2b + (size_t)slice * 65536, (unsigned short*)0, 0, bx * 64);
}

// ---------------------------------------------------------------------------
// K4 final (R12 P4, proven): out[b,n,o] = sum_d emb[n,d]*(xg@WpT_d) + bias.
// Per d: stage swizzled wpTb[d] (48 KB) into LDS via DMA, 20 MFMA/wave.
// 4 nodes/block (nd = wave>>1), 2 o-halves (oh). grid 256, block 512.
// ---------------------------------------------------------------------------
__global__ __launch_bounds__(512, 4) void final_kernel(
    const unsigned short* __restrict__ X0b,
    const unsigned short* __restrict__ X1b,
    const unsigned short* __restrict__ X2b,
    const unsigned short* __restrict__ wpTb, const float* __restrict__ emb,
    const float* __restrict__ bp, float* __restrict__ out) {
  __shared__ __align__(16) unsigned short wd[64][384];          // 48 KB
  const int tid = threadIdx.x, bid = blockIdx.x;
  const int wave = tid >> 6, lane = tid & 63;
  const int l15 = lane & 15, q = lane >> 4;
  const int nd = wave >> 1, oh = wave & 1;
  const int n = bid * 4 + nd;
  const int sw2 = l15 & 7;

  FragU af10[10];
#pragma unroll
  for (int ks = 0; ks < 10; ++ks) {
    const int k = ks >> 1;
    const int cc0 = (ks & 1) * 32 + q * 8;
    const unsigned short* srcp;
    if (k == 0) {
      srcp = X0b + ((size_t)l15 * 1024 + n) * 64 + cc0;
    } else {
      const unsigned short* arr = (k == 1 || k == 3) ? X1b : X2b;
      const int s = (k >= 3) ? 1 : 0;
      srcp = arr + ((size_t)(s * 16 + l15) * 1024 + n) * 64 + cc0;
    }
    af10[ks].s = *(const s16x8*)srcp;
  }

  f32x4 acc0 = {0.f, 0.f, 0.f, 0.f}, acc1 = {0.f, 0.f, 0.f, 0.f};
  // Per-lane global source; LDS dest wave-uniform + lane*16B (linear copy,
  // swizzle baked into wpTb's global layout).
  const unsigned short* wsrc = wpTb + (size_t)wave * 3072 + lane * 8;
  unsigned short* wdst = (unsigned short*)wd + wave * 3072;
#pragma unroll 1
  for (int d = 0; d < 10; ++d) {
    if (d) __syncthreads();                          // WAR vs prev compute
#pragma unroll
    for (int i = 0; i < 6; ++i)
      async_cp16(wsrc + (size_t)d * 24576 + i * 512, wdst + i * 512);
    asm volatile("s_waitcnt vmcnt(0)" ::: "memory");
    __builtin_amdgcn_sched_barrier(0);
    __syncthreads();
    f32x4 t0 = {0.f, 0.f, 0.f, 0.f}, t1 = {0.f, 0.f, 0.f, 0.f};
#pragma unroll
    for (int ks = 0; ks < 10; ++ks) {
      const int p = ((ks * 4 + q) ^ sw2) * 8;
      FragU b0, b1;
      b0.s = *(const s16x8*)&wd[oh * 32 + l15][p];
      b1.s = *(const s16x8*)&wd[oh * 32 + 16 + l15][p];
      t0 = __builtin_amdgcn_mfma_f32_16x16x32_bf16(af10[ks].b, b0.b, t0,
                                                   0, 0, 0);
      t1 = __builtin_amdgcn_mfma_f32_16x16x32_bf16(af10[ks].b, b1.b, t1,
                                                   0, 0, 0);
    }
    const float e = emb[n * 10 + d];
#pragma unroll
    for (int rr = 0; rr < 4; ++rr) {
      acc0[rr] += e * t0[rr];
      acc1[rr] += e * t1[rr];
    }
  }

#pragma unroll
  for (int tt = 0; tt < 2; ++tt) {
    const int o = oh * 32 + tt * 16 + l15;
    float bv = 0.f;
#pragma unroll
    for (int d = 0; d < 10; ++d) bv += emb[n * 10 + d] * bp[d * 64 + o];
#pragma unroll
    for (int rr = 0; rr < 4; ++rr) {
      const int bb = q * 4 + rr;
      const float a = tt ? acc1[rr] : acc0[rr];
      out[((size_t)bb * 1024 + n) * 64 + o] = a + bv;
    }
  }
}

// ---------------------------------------------------------------------------
extern "C" void kernel_launch(void* const* d_in, const int* in_sizes, int n_in,
                              void* d_out, int out_size, void* d_ws,
                              size_t ws_size, hipStream_t stream) {
  const float* x   = (const float*)d_in[0];   // [16,1024,64]
  const float* adj = (const float*)d_in[1];   // [2,16,1024,1024]
  const float* emb = (const float*)d_in[2];   // [1024,10]
  const float* wp  = (const float*)d_in[3];   // [10,5,64,64]
  const float* bp  = (const float*)d_in[4];   // [10,64]
  float* out = (float*)d_out;                 // [16,1024,64]

  char* ws = (char*)d_ws;
  unsigned short* adjb = (unsigned short*)(ws);                      // 67 MB
  unsigned short* XT0  = (unsigned short*)(ws + ((size_t)68 << 20)); // 2 MB
  unsigned short* XT1  = (unsigned short*)(ws + ((size_t)70 << 20)); // 4 MB
  unsigned short* X0b  = (unsigned short*)(ws + ((size_t)74 << 20)); // 2 MB
  unsigned short* X1b  = (unsigned short*)(ws + ((size_t)76 << 20)); // 4 MB
  unsigned short* X2b  = (unsigned short*)(ws + ((size_t)80 << 20)); // 4 MB
  unsigned short* wpTb = (unsigned short*)(ws + ((size_t)84 << 20)); // 480 KB

  cvt_adj<<<dim3(8192), dim3(256), 0, stream>>>(adj, adjb);
  prep<<<dim3(306), dim3(256), 0, stream>>>(x, wp, XT0, X0b, wpTb);
  hop1_kernel<<<dim3(16, 32), dim3(256), 0, stream>>>(adjb, XT0, X1b, XT1);
  hop2_kernel<<<dim3(16, 32), dim3(256), 0, stream>>>(adjb, XT1, X2b);
  final_kernel<<<dim3(256), dim3(512), 0, stream>>>(X0b, X1b, X2b, wpTb, emb,
                                                    bp, out);
}